// Round 9
// baseline (394.659 us; speedup 1.0000x reference)
//
#include <hip/hip_runtime.h>
#include <hip/hip_bf16.h>
#include <math.h>

// Problem constants
#define NN 325            // nodes (attention sequence length)
#define NROWS (8*325*64)  // 166400 flat rows of width 64
#define RELEM ((size_t)NROWS * 64)
#define NTILES (NROWS/16) // 10400 16-row tiles
#define QSC 0.36067376022224085f   // 0.25 * log2(e): exp2-domain softmax
#define QT2 11            // ceil(325/32): 32-wide attention tiles

using bf16x8 = __attribute__((ext_vector_type(8))) short;
using f32x4  = __attribute__((ext_vector_type(4))) float;
using f32x16 = __attribute__((ext_vector_type(16))) float;
using u32x2  = __attribute__((ext_vector_type(2))) unsigned;

union BF8 { bf16x8 v; unsigned u[4]; };

// float -> bf16 bits, RNE (scalar; used in prep only)
static __device__ inline short f2bf(float f) {
    unsigned u = __float_as_uint(f);
    unsigned r = (u + 0x7fffu + ((u >> 16) & 1u)) >> 16;
    return (short)r;
}
// packed pair: low 16 = bf16(a), high 16 = bf16(b)
static __device__ inline unsigned pk2(float a, float b) {
    __hip_bfloat162 h = __float22bfloat162_rn(make_float2(a, b));
    union { __hip_bfloat162 h; unsigned u; } c; c.h = h; return c.u;
}
// async global->LDS, 16B per lane; LDS dest = uniform base + lane*16
static __device__ inline void gload16(const void* g, void* l) {
    __builtin_amdgcn_global_load_lds(
        (const __attribute__((address_space(1))) void*)g,
        (__attribute__((address_space(3))) void*)l, 16, 0, 0);
}
// zero p unless bit r of mw is set (mask applied post-exp2: inf/NaN -> +0.0)
static __device__ inline float maskp(float p, unsigned mw, int r) {
    unsigned keep = (unsigned)((int)(mw << (31 - r)) >> 31);
    return __uint_as_float(__float_as_uint(p) & keep);
}

// exp2+mask+pack+permlane one 32x32 S^T tile into PV A-frags, accumulate.
// s[r] = S^T frag; mw = validity bits; vrow = V^T row base; kt2 = tile idx.
static __device__ inline void tile_pv(const f32x16& s, unsigned mw,
                                      const short* vrow, int kt2,
                                      f32x16& acc) {
    float p[16];
#pragma unroll
    for (int r = 0; r < 16; ++r)
        p[r] = maskp(__builtin_amdgcn_exp2f(s[r]), mw, r);
    unsigned w0 = pk2(p[0],  p[1]),  w1 = pk2(p[2],  p[3]);
    unsigned w2 = pk2(p[4],  p[5]),  w3 = pk2(p[6],  p[7]);
    unsigned w4 = pk2(p[8],  p[9]),  w5 = pk2(p[10], p[11]);
    unsigned w6 = pk2(p[12], p[13]), w7 = pk2(p[14], p[15]);
    u32x2 s02 = __builtin_amdgcn_permlane32_swap(w0, w2, false, false);
    u32x2 s13 = __builtin_amdgcn_permlane32_swap(w1, w3, false, false);
    u32x2 s46 = __builtin_amdgcn_permlane32_swap(w4, w6, false, false);
    u32x2 s57 = __builtin_amdgcn_permlane32_swap(w5, w7, false, false);
    BF8 pa0, pa1;
    pa0.u[0] = s02[0]; pa0.u[1] = s13[0]; pa0.u[2] = s02[1]; pa0.u[3] = s13[1];
    pa1.u[0] = s46[0]; pa1.u[1] = s57[0]; pa1.u[2] = s46[1]; pa1.u[3] = s57[1];
    bf16x8 v0 = *(const bf16x8*)(vrow + kt2 * 32);
    bf16x8 v1 = *(const bf16x8*)(vrow + kt2 * 32 + 16);
    acc = __builtin_amdgcn_mfma_f32_32x32x16_bf16(pa0.v, v0, acc, 0, 0, 0);
    acc = __builtin_amdgcn_mfma_f32_32x32x16_bf16(pa1.v, v1, acc, 0, 0, 0);
}

// ---------------------------------------------------------------------------
// Kernel 0: pack 6 weight matrices into MFMA-A-frag-linear hi/lo bf16 planes.
// Matrices (all A[m][k], 64x64): 0: W_in^T  1..3: in_proj rows q,k,v
//                                4: out_w   5: W_out
// Layout: Wp[mat*8192 + (mt*2+kc)*1024 + plane*512 + lane*8 + j]
//   element A[m = mt*16 + (lane&15)][k = kc*32 + (lane>>4)*8 + j]
// ---------------------------------------------------------------------------
__global__ __launch_bounds__(256) void kprep(const float* __restrict__ Win,
                                             const float* __restrict__ ipw,
                                             const float* __restrict__ outw,
                                             const float* __restrict__ wout,
                                             short* __restrict__ Wp) {
    int idx = blockIdx.x * 256 + threadIdx.x;   // 6*4096 = 24576
    if (idx >= 24576) return;
    int mat = idx >> 12, ft = (idx >> 9) & 7, lane = (idx >> 3) & 63, j = idx & 7;
    int m = (ft >> 1) * 16 + (lane & 15);
    int k = (ft & 1) * 32 + (lane >> 4) * 8 + j;
    float w;
    if (mat == 0)      w = Win[k * 64 + m];               // W_in^T
    else if (mat <= 3) w = ipw[((mat - 1) * 64 + m) * 64 + k];
    else if (mat == 4) w = outw[m * 64 + k];
    else               w = wout[m * 64 + k];
    short hi = f2bf(w);
    float hif = __uint_as_float(((unsigned)(unsigned short)hi) << 16);
    short lo = f2bf(w - hif);
    int base = mat * 8192 + ft * 1024 + lane * 8 + j;
    Wp[base] = hi;
    Wp[base + 512] = lo;
}

// ---------------------------------------------------------------------------
// Kernel 0b: adjacency -> per-lane 16-bit mask words, pre-permuted to the
// 32x32 S^T fragment layout. Bit r of Mg[(qt2*11+kt2)*64+lane] = valid for
//   q = qt2*32 + (lane&31), key = kt2*32 + (r&3) + 8*(r>>2) + 4*(lane>>5).
// 31 KB total, L2/L1-resident; one dword load per lane per tile in kattn.
// ---------------------------------------------------------------------------
__global__ __launch_bounds__(256) void kbias(const int* __restrict__ adj,
                                             unsigned* __restrict__ Mg) {
    int idx = blockIdx.x * 256 + threadIdx.x;   // 11*11*64 = 7744
    if (idx >= QT2 * QT2 * 64) return;
    int lane = idx & 63, kt2 = (idx >> 6) % QT2, qt2 = idx / (QT2 * 64);
    int l31 = lane & 31, hi = lane >> 5;
    int q = qt2 * 32 + l31;
    unsigned m = 0;
#pragma unroll
    for (int r = 0; r < 16; ++r) {
        int key = kt2 * 32 + (r & 3) + 8 * (r >> 2) + 4 * hi;
        bool valid = (q < NN) && (key < NN) &&
                     (q == key || adj[q * NN + key] != 0);
        m |= (valid ? 1u : 0u) << r;
    }
    Mg[idx] = m;
}

// ---------------------------------------------------------------------------
// Kernel 1: fused x -> h -> Q,K,V via bf16x3 MFMA (unchanged from r6/r8).
// LDS weight staging; dense global_load_lds x-stage; head-major stores.
// LDS 80KB -> 2 blocks/CU.
// ---------------------------------------------------------------------------
__global__ __launch_bounds__(256, 2) void kqkv(const float* __restrict__ X,
                                               const float* __restrict__ bin,
                                               const float* __restrict__ ipb,
                                               const short* __restrict__ Wp,
                                               short* __restrict__ Q,
                                               short* __restrict__ Kb,
                                               short* __restrict__ Vb) {
    __shared__ short wl[32768];     // mats 0..3 frag-linear (65,536 B)
    __shared__ __align__(16) short hf[4][2048];   // per-wave x-stage/h-frag overlay
    int tid = threadIdx.x;
    {   // stage weights (one-time)
        const uint4* src = (const uint4*)Wp;
        uint4* dst = (uint4*)wl;
#pragma unroll
        for (int i = 0; i < 16; ++i) dst[tid + i * 256] = src[tid + i * 256];
    }
    __syncthreads();

    int wave = tid >> 6, lane = tid & 63, quad = lane >> 4, l15 = lane & 15;
    short* hfw = hf[wave];
    char* hfb = (char*)hfw;

    int srow = lane >> 4;       // staging: row within 4-row group
    int sslot = lane & 15;      // staging: LDS 16B slot within row
    int stride = gridDim.x * 4;

    int tile = blockIdx.x * 4 + wave;
    {   // prologue: stage x(tile): instr i covers rows 4i..4i+3 densely
        const char* xt = (const char*)X + (size_t)tile * 4096;
#pragma unroll
        for (int i = 0; i < 4; ++i) {
            int r = i * 4 + srow;
            gload16(xt + r * 256 + ((sslot ^ r) << 4), hfb + i * 1024 + lane * 16);
        }
    }

    while (tile < NTILES) {
        asm volatile("s_waitcnt vmcnt(0)" ::: "memory");
        __builtin_amdgcn_sched_barrier(0);

        // ---- x B-frags from swizzled LDS (fp32 -> hi/lo bf16) ----
        BF8 xbh[2], xbl[2];
#pragma unroll
        for (int kc = 0; kc < 2; ++kc) {
            float e[8];
#pragma unroll
            for (int h = 0; h < 2; ++h) {
                int slot = (kc * 8 + quad * 2 + h) ^ l15;
                float4 v = *(const float4*)(hfb + l15 * 256 + slot * 16);
                e[h * 4 + 0] = v.x; e[h * 4 + 1] = v.y;
                e[h * 4 + 2] = v.z; e[h * 4 + 3] = v.w;
            }
            unsigned hh[4], ll[4];
#pragma unroll
            for (int p = 0; p < 4; ++p) {
                hh[p] = pk2(e[2 * p], e[2 * p + 1]);
                float f0 = __uint_as_float(hh[p] << 16);
                float f1 = __uint_as_float(hh[p] & 0xFFFF0000u);
                ll[p] = pk2(e[2 * p] - f0, e[2 * p + 1] - f1);
            }
#pragma unroll
            for (int p = 0; p < 4; ++p) { xbh[kc].u[p] = hh[p]; xbl[kc].u[p] = ll[p]; }
        }

        // ---- GEMM1: h^T = W_in^T x^T + b_in ----
#pragma unroll
        for (int mt = 0; mt < 4; ++mt) {
            float4 bv = *(const float4*)(bin + mt * 16 + quad * 4);
            f32x4 acc = {bv.x, bv.y, bv.z, bv.w};
#pragma unroll
            for (int kc = 0; kc < 2; ++kc) {
                const short* ap = wl + (mt * 2 + kc) * 1024 + lane * 8;
                bf16x8 ah = *(const bf16x8*)ap;
                bf16x8 al = *(const bf16x8*)(ap + 512);
                acc = __builtin_amdgcn_mfma_f32_16x16x32_bf16(ah, xbh[kc].v, acc, 0, 0, 0);
                acc = __builtin_amdgcn_mfma_f32_16x16x32_bf16(ah, xbl[kc].v, acc, 0, 0, 0);
                acc = __builtin_amdgcn_mfma_f32_16x16x32_bf16(al, xbh[kc].v, acc, 0, 0, 0);
            }
            // write h hi/lo frags: F = mt*16+quad*4+r, R = l15
            int kc2 = mt >> 1;
            int lane2 = ((mt & 1) * 2 + (quad >> 1)) * 16 + l15;
            int jb = (quad & 1) * 4;
            unsigned u01 = pk2(acc[0], acc[1]), u23 = pk2(acc[2], acc[3]);
            uint2 wh; wh.x = u01; wh.y = u23;
            *(uint2*)(hfw + kc2 * 1024 + lane2 * 8 + jb) = wh;
            float f0 = __uint_as_float(u01 << 16), f1 = __uint_as_float(u01 & 0xFFFF0000u);
            float f2 = __uint_as_float(u23 << 16), f3 = __uint_as_float(u23 & 0xFFFF0000u);
            uint2 wlo; wlo.x = pk2(acc[0] - f0, acc[1] - f1);
            wlo.y = pk2(acc[2] - f2, acc[3] - f3);
            *(uint2*)(hfw + kc2 * 1024 + 512 + lane2 * 8 + jb) = wlo;
        }

        // ---- h B-frags (wave-private readback) ----
        BF8 hbh[2], hbl[2];
#pragma unroll
        for (int kc = 0; kc < 2; ++kc) {
            hbh[kc].v = *(const bf16x8*)(hfw + kc * 1024 + lane * 8);
            hbl[kc].v = *(const bf16x8*)(hfw + kc * 1024 + 512 + lane * 8);
        }

        // drain LDS reads, then overlay-stage next tile (h region dead)
        asm volatile("s_waitcnt lgkmcnt(0)" ::: "memory");
        __builtin_amdgcn_sched_barrier(0);

        int nt = tile + stride;
        if (nt < NTILES) {
            const char* xt = (const char*)X + (size_t)nt * 4096;
#pragma unroll
            for (int i = 0; i < 4; ++i) {
                int r = i * 4 + srow;
                gload16(xt + r * 256 + ((sslot ^ r) << 4), hfb + i * 1024 + lane * 16);
            }
        }

        // ---- GEMM2-4: q^T,k^T,v^T = W_t h^T + b_t ----
        size_t row = (size_t)tile * 16 + l15;
#pragma unroll
        for (int t = 0; t < 3; ++t) {
            short* Out = (t == 0) ? Q : (t == 1) ? Kb : Vb;
            float sc = (t == 0) ? QSC : 1.0f;
#pragma unroll
            for (int mt = 0; mt < 4; ++mt) {
                float4 bv = *(const float4*)(ipb + t * 64 + mt * 16 + quad * 4);
                f32x4 acc = {bv.x, bv.y, bv.z, bv.w};
#pragma unroll
                for (int kc = 0; kc < 2; ++kc) {
                    const short* ap = wl + (1 + t) * 8192 + (mt * 2 + kc) * 1024 + lane * 8;
                    bf16x8 ah = *(const bf16x8*)ap;
                    bf16x8 al = *(const bf16x8*)(ap + 512);
                    acc = __builtin_amdgcn_mfma_f32_16x16x32_bf16(ah, hbh[kc].v, acc, 0, 0, 0);
                    acc = __builtin_amdgcn_mfma_f32_16x16x32_bf16(ah, hbl[kc].v, acc, 0, 0, 0);
                    acc = __builtin_amdgcn_mfma_f32_16x16x32_bf16(al, hbh[kc].v, acc, 0, 0, 0);
                }
                uint2 st; st.x = pk2(acc[0] * sc, acc[1] * sc);
                st.y = pk2(acc[2] * sc, acc[3] * sc);
                // head-major store: head == mt; 64 lanes -> 512B contiguous
                *(uint2*)(Out + ((size_t)mt * NROWS + row) * 16 + quad * 4) = st;
            }
        }
        tile = nt;
    }
}

// ---------------------------------------------------------------------------
// Kernel 2: masked MHA, swapped-QK^T 32x32x16 structure.
//  Round-9: ILP restore at constant occupancy. r8 showed VALU-issue-bound
//  (VALUBusy 62%, busy-time matches instr count) with 38% stall: the 40-VGPR
//  schedule serialized exp/pack chains and acc(t+1) waits on acc(t)'s PV.
//  - kt2 fully unrolled in PAIRS: two S-MFMAs issue back-to-back; tile b's
//    exp/pack overlaps tile a's PV.
//  - TWO accumulators (acc0/acc1, summed at epilogue) break the PV chain.
//  - __launch_bounds__(512,4): VGPR cap 128 so both chains stay in regs
//    (cap 16 waves/CU = measured current residency -> single-variable test).
// ---------------------------------------------------------------------------
__global__ __launch_bounds__(512, 4) void kattn(const short* __restrict__ Q,
                                                const short* __restrict__ K,
                                                const short* __restrict__ V,
                                                const unsigned* __restrict__ Mg,
                                                float* __restrict__ O) {
    __shared__ __align__(16) short vsT[17 * 360];     // [d][kn] + ones row 16

    // XCD-aware decode: xcd = b&7, slot = b>>3; i = (slot>>2)*8 + xcd,
    // head = slot&3. Bijective over 2048 = 512 i x 4 heads.
    int b = blockIdx.x;
    int xcd = b & 7, slot = b >> 3;
    int i = (slot >> 2) * 8 + xcd, head = slot & 3;
    const short* Kg  = K + ((size_t)head * NROWS + (size_t)i * NN) * 16;
    const short* Vbp = V + ((size_t)head * NROWS + (size_t)i * NN) * 16;
    const short* Qb  = Q + ((size_t)head * NROWS + (size_t)i * NN) * 16;
    float*       Ob  = O + ((size_t)head * NROWS + (size_t)i * NN) * 16;
    int tid = threadIdx.x;

    for (int kn = tid; kn < 352; kn += 512) {
        bf16x8 va = {0,0,0,0,0,0,0,0}, vb = {0,0,0,0,0,0,0,0};
        if (kn < NN) {
            va = *(const bf16x8*)(Vbp + (size_t)kn * 16);
            vb = *(const bf16x8*)(Vbp + (size_t)kn * 16 + 8);
        }
#pragma unroll
        for (int d = 0; d < 8; ++d) vsT[d * 360 + kn] = va[d];
#pragma unroll
        for (int d = 0; d < 8; ++d) vsT[(8 + d) * 360 + kn] = vb[d];
    }
    for (int kn = tid; kn < 360; kn += 512) vsT[16 * 360 + kn] = (short)0x3F80; // 1.0
    __syncthreads();   // the only barrier

    int wave = tid >> 6, lane = tid & 63;
    int l31 = lane & 31, hi = lane >> 5, l15 = lane & 15;
    // B-frag V row: d = lane&31 for d<16, else the ones row (broadcast)
    const short* vrow = vsT + (l31 < 16 ? l31 : 16) * 360 + hi * 8;
    const short* kgl = Kg + (size_t)l31 * 16 + hi * 8;   // per-lane K base

    f32x16 cz = {};   // loop-invariant zero C-operand

    for (int qt2 = wave; qt2 < QT2; qt2 += 8) {
        int qr = qt2 * 32 + l31; if (qr > NN - 1) qr = NN - 1;     // dup pad rows
        bf16x8 bq = *(const bf16x8*)(Qb + (size_t)qr * 16 + hi * 8);
        f32x16 acc0 = {}, acc1 = {};
        const unsigned* mgp = Mg + (size_t)(qt2 * QT2) * 64 + lane;

        // prefetch tiles 0,1 (K from global/L2; compile-time offsets below)
        bf16x8 ak0 = *(const bf16x8*)(kgl);
        bf16x8 ak1 = *(const bf16x8*)(kgl + 512);
        unsigned mw0 = mgp[0], mw1 = mgp[64];

#pragma unroll
        for (int u = 0; u < 5; ++u) {
            int ta = 2 * u, tb = 2 * u + 1;
            // two independent S-MFMAs issue back-to-back
            f32x16 s0 = __builtin_amdgcn_mfma_f32_32x32x16_bf16(ak0, bq, cz, 0, 0, 0);
            f32x16 s1 = __builtin_amdgcn_mfma_f32_32x32x16_bf16(ak1, bq, cz, 0, 0, 0);

            // prefetch next pair (compile-time indices; wrap keeps in-range)
            int tna = (tb + 1 <= QT2 - 1) ? tb + 1 : 0;
            int tnb = (tb + 2 <= QT2 - 1) ? tb + 2 : 0;
            bf16x8 akn0 = *(const bf16x8*)(kgl + (size_t)tna * 512);
            bf16x8 akn1 = *(const bf16x8*)(kgl + (size_t)tnb * 512);
            unsigned mwn0 = mgp[tna * 64], mwn1 = mgp[tnb * 64];

            // exp/mask/pack/PV: independent chains into acc0 / acc1
            tile_pv(s0, mw0, vrow, ta, acc0);
            tile_pv(s1, mw1, vrow, tb, acc1);

            ak0 = akn0; ak1 = akn1; mw0 = mwn0; mw1 = mwn1;
        }
        {   // tail tile 10 (ak0/mw0 hold it after the loop)
            f32x16 s0 = __builtin_amdgcn_mfma_f32_32x32x16_bf16(ak0, bq, cz, 0, 0, 0);
            tile_pv(s0, mw0, vrow, QT2 - 1, acc0);
        }

        // acc[r]: D[q = qt2*32 + (r&3)+8*(r>>2)+4*hi][col = lane&31]
        //   cols 0..15 numerator (d), cols 16..31 denominator.
#pragma unroll
        for (int r = 0; r < 16; ++r) {
            float a = acc0[r] + acc1[r];
            float den = __shfl_xor(a, 16, 64);
            float inv = __builtin_amdgcn_rcpf(den);
            inv = inv * (2.0f - den * inv);          // 1 Newton step: ~1ulp
            int qn = qt2 * 32 + (r & 3) + 8 * (r >> 2) + 4 * hi;
            if (l31 < 16 && qn < NN)
                Ob[(size_t)qn * 16 + l15] = a * inv;
        }
    }
}

// ---------------------------------------------------------------------------
// Kernel 3: o -> out_proj -> W_out -> exact GELU -> transposed store
// (unchanged from r6/r8). LDS 48KB -> 3 blocks/CU.
// ---------------------------------------------------------------------------
__global__ __launch_bounds__(256, 2) void kfinal(const float* __restrict__ Ob,
                                                 const float* __restrict__ outb,
                                                 const float* __restrict__ boutv,
                                                 const short* __restrict__ Wp,
                                                 float* __restrict__ Yout) {
    __shared__ short wl[16384];     // mats 4,5 (32,768 B)
    __shared__ __align__(16) short hf[4][2048];   // t1 frags, then y-transpose
    int tid = threadIdx.x;
    {
        const uint4* src = (const uint4*)Wp;
        uint4* dst = (uint4*)wl;
#pragma unroll
        for (int i = 0; i < 8; ++i) dst[tid + i * 256] = src[4096 + tid + i * 256];
    }
    __syncthreads();

    int wave = tid >> 6, lane = tid & 63, quad = lane >> 4, l15 = lane & 15;
    short* hfw = hf[wave];

    for (int tile = blockIdx.x * 4 + wave; tile < NTILES; tile += gridDim.x * 4) {
        size_t row = (size_t)tile * 16 + l15;

        BF8 obh[2], obl[2];
#pragma unroll
        for (int kc = 0; kc < 2; ++kc) {
            // head-major O: h = kc*32+quad*8 -> head = kc*2+(quad>>1),
            // idx = (quad&1)*8
            const float* xp = Ob + ((size_t)(kc * 2 + (quad >> 1)) * NROWS + row) * 16
                              + (quad & 1) * 8;
            float4 v0 = *(const float4*)xp;
            float4 v1 = *(const float4*)(xp + 4);
            float e[8] = {v0.x, v0.y, v0.z, v0.w, v1.x, v1.y, v1.z, v1.w};
            unsigned hh[4], ll[4];
#pragma unroll
            for (int p = 0; p < 4; ++p) {
                hh[p] = pk2(e[2 * p], e[2 * p + 1]);
                float f0 = __uint_as_float(hh[p] << 16);
                float f1 = __uint_as_float(hh[p] & 0xFFFF0000u);
                ll[p] = pk2(e[2 * p] - f0, e[2 * p + 1] - f1);
            }
#pragma unroll
            for (int p = 0; p < 4; ++p) { obh[kc].u[p] = hh[p]; obl[kc].u[p] = ll[p]; }
        }

        // GEMM5: t1^T = out_w o^T + out_b
#pragma unroll
        for (int mt = 0; mt < 4; ++mt) {
            float4 bv = *(const float4*)(outb + mt * 16 + quad * 4);
            f32x4 acc = {bv.x, bv.y, bv.z, bv.w};
#pragma unroll
            for (int kc = 0; kc < 2; ++kc) {
                const short* ap = wl + (mt * 2 + kc) * 1024 + lane * 8;
                bf16x8 ah = *(const bf16x8*)ap;
                bf16x8 al = *(const bf16x8*)(ap + 512);
                acc = __builtin_amdgcn_mfma_f32_16x16x32_bf16(ah, obh[kc].v, acc, 0, 0, 0);
                acc = __builtin_amdgcn_mfma_f32_16x16x32_bf16(ah, obl[kc].v, acc, 0, 0, 0);
                acc = __builtin_amdgcn_mfma_f32_16x16x32_bf16(al, obh[kc].v, acc, 0, 0, 0);
            }
            int kc2 = mt >> 1;
            int lane2 = ((mt & 1) * 2 + (quad >> 1)) * 16 + l15;
            int jb = (quad & 1) * 4;
            unsigned u01 = pk2(acc[0], acc[1]), u23 = pk2(acc[2], acc[3]);
            uint2 wh; wh.x = u01; wh.y = u23;
            *(uint2*)(hfw + kc2 * 1024 + lane2 * 8 + jb) = wh;
            float f0 = __uint_as_float(u01 << 16), f1 = __uint_as_float(u01 & 0xFFFF0000u);
            float f2 = __uint_as_float(u23 << 16), f3 = __uint_as_float(u23 & 0xFFFF0000u);
            uint2 wlo; wlo.x = pk2(acc[0] - f0, acc[1] - f1);
            wlo.y = pk2(acc[2] - f2, acc[3] - f3);
            *(uint2*)(hfw + kc2 * 1024 + 512 + lane2 * 8 + jb) = wlo;
        }

        BF8 tbh[2], tbl[2];
#pragma unroll
        for (int kc = 0; kc < 2; ++kc) {
            tbh[kc].v = *(const bf16x8*)(hfw + kc * 1024 + lane * 8);
            tbl[kc].v = *(const bf16x8*)(hfw + kc * 1024 + 512 + lane * 8);
        }

        // GEMM6: y^T = W_out t1^T + b_out; GELU; LDS transpose; 256B stores
        float* yf = (float*)hfw;     // t1 frags dead after tbh/tbl readback
#pragma unroll
        for (int mt = 0; mt < 4; ++mt) {
            float4 bv = *(const float4*)(boutv + mt * 16 + quad * 4);
            f32x4 acc = {bv.x, bv.y, bv.z, bv.w};
#pragma unroll
            for (int kc = 0; kc < 2; ++kc) {
                const short* ap = wl + 8192 + (mt * 2 + kc) * 1024 + lane * 8;
                bf16x8 ah = *(const bf16x8*)ap;
                bf16x8 al = *(const bf16x8*)(ap + 512);
                acc = __builtin_amdgcn_mfma_f32_16x16x32_bf16(ah, tbh[kc].v, acc, 0, 0, 0);
                acc = __builtin_amdgcn_mfma_f32_16x16x32_bf16(ah, tbl[kc].v, acc, 0, 0, 0);
                acc = __builtin_amdgcn_mfma_f32_16x16x32_bf16(al, tbh[kc].v, acc, 0, 0, 0);
            }
            float4 yv;
            yv.x = 0.5f * acc[0] * (1.0f + erff(acc[0] * 0.70710678118654752f));
            yv.y = 0.5f * acc[1] * (1.0f + erff(acc[1] * 0.70710678118654752f));
            yv.z = 0.5f * acc[2] * (1.0f + erff(acc[2] * 0.70710678118654752f));
            yv.w = 0.5f * acc[3] * (1.0f + erff(acc[3] * 0.70710678118654752f));
            int cblk = mt * 4 + quad;                 // 4-float column block
            int pos = cblk ^ (l15 & 7);               // bank-spread swizzle
            *(float4*)(yf + l15 * 64 + pos * 4) = yv;
        }
#pragma unroll
        for (int s = 0; s < 4; ++s) {
            int rr = s * 4 + (lane >> 4);             // row within tile
            float4 w = *(const float4*)(yf + rr * 64 + ((l15 ^ (rr & 7)) * 4));
            unsigned rw2 = (unsigned)(tile * 16 + rr);
            unsigned ii2 = rw2 / NN, n2 = rw2 - ii2 * NN;
            size_t ob2 = (((size_t)(ii2 >> 6) * NN + n2) * 64 + (ii2 & 63)) * 64;
            *(float4*)(Yout + ob2 + l15 * 4) = w;     // 16 lanes = 256B row
        }
    }
}

// ---------------------------------------------------------------------------
extern "C" void kernel_launch(void* const* d_in, const int* in_sizes, int n_in,
                              void* d_out, int out_size, void* d_ws, size_t ws_size,
                              hipStream_t stream) {
    const float* x    = (const float*)d_in[0];
    const int*   adj  = (const int*)  d_in[1];
    const float* W_in = (const float*)d_in[2];
    const float* b_in = (const float*)d_in[3];
    const float* ipw  = (const float*)d_in[4];
    const float* ipb  = (const float*)d_in[5];
    const float* outw = (const float*)d_in[6];
    const float* outb = (const float*)d_in[7];
    const float* wout = (const float*)d_in[8];
    const float* bout = (const float*)d_in[9];
    float* out = (float*)d_out;

    char* wsb = (char*)d_ws;
    short* bufQ = (short*)(wsb);                        // 2*RELEM B (head-major)
    short* bufK = (short*)(wsb + 2 * RELEM);
    short* bufV = (short*)(wsb + 4 * RELEM);
    float* bufO = (float*)(wsb + 6 * RELEM);            // 4*RELEM B (head-major)
    short* Wp   = (short*)(wsb + 10 * RELEM);           // 98,304 B
    unsigned* Mg = (unsigned*)(wsb + 10 * RELEM + 98304); // 11*11*64*4 = 30,976 B

    hipLaunchKernelGGL(kprep,  dim3(96),  dim3(256), 0, stream, W_in, ipw, outw, wout, Wp);
    hipLaunchKernelGGL(kbias,  dim3(31),  dim3(256), 0, stream, adj, Mg);
    hipLaunchKernelGGL(kqkv,   dim3(512), dim3(256), 0, stream,
                       x, b_in, ipb, Wp, bufQ, bufK, bufV);
    hipLaunchKernelGGL(kattn,  dim3(512 * 4), dim3(512), 0, stream,
                       bufQ, bufK, bufV, Mg, bufO);
    hipLaunchKernelGGL(kfinal, dim3(768), dim3(256), 0, stream,
                       bufO, outb, bout, Wp, out);
}

// Round 10
// 206.702 us; speedup vs baseline: 1.9093x; 1.9093x over previous
//
#include <hip/hip_runtime.h>
#include <hip/hip_bf16.h>
#include <math.h>

// Problem constants
#define NN 325            // nodes (attention sequence length)
#define NROWS (8*325*64)  // 166400 flat rows of width 64
#define RELEM ((size_t)NROWS * 64)
#define NTILES (NROWS/16) // 10400 16-row tiles
#define QSC 0.36067376022224085f   // 0.25 * log2(e): exp2-domain softmax
#define QT2 11            // ceil(325/32): 32-wide attention tiles

using bf16x8 = __attribute__((ext_vector_type(8))) short;
using f32x4  = __attribute__((ext_vector_type(4))) float;
using f32x16 = __attribute__((ext_vector_type(16))) float;
using u32x2  = __attribute__((ext_vector_type(2))) unsigned;

union BF8 { bf16x8 v; unsigned u[4]; };

// float -> bf16 bits, RNE (scalar; used in prep only)
static __device__ inline short f2bf(float f) {
    unsigned u = __float_as_uint(f);
    unsigned r = (u + 0x7fffu + ((u >> 16) & 1u)) >> 16;
    return (short)r;
}
// packed pair: low 16 = bf16(a), high 16 = bf16(b)
static __device__ inline unsigned pk2(float a, float b) {
    __hip_bfloat162 h = __float22bfloat162_rn(make_float2(a, b));
    union { __hip_bfloat162 h; unsigned u; } c; c.h = h; return c.u;
}
// async global->LDS, 16B per lane; LDS dest = uniform base + lane*16
static __device__ inline void gload16(const void* g, void* l) {
    __builtin_amdgcn_global_load_lds(
        (const __attribute__((address_space(1))) void*)g,
        (__attribute__((address_space(3))) void*)l, 16, 0, 0);
}
// zero p unless bit r of mw is set (mask applied post-exp2: inf/NaN -> +0.0)
static __device__ inline float maskp(float p, unsigned mw, int r) {
    unsigned keep = (unsigned)((int)(mw << (31 - r)) >> 31);
    return __uint_as_float(__float_as_uint(p) & keep);
}

// ---------------------------------------------------------------------------
// Kernel 0: pack 6 weight matrices into MFMA-A-frag-linear hi/lo bf16 planes.
// Matrices (all A[m][k], 64x64): 0: W_in^T  1..3: in_proj rows q,k,v
//                                4: out_w   5: W_out
// Layout: Wp[mat*8192 + (mt*2+kc)*1024 + plane*512 + lane*8 + j]
//   element A[m = mt*16 + (lane&15)][k = kc*32 + (lane>>4)*8 + j]
// ---------------------------------------------------------------------------
__global__ __launch_bounds__(256) void kprep(const float* __restrict__ Win,
                                             const float* __restrict__ ipw,
                                             const float* __restrict__ outw,
                                             const float* __restrict__ wout,
                                             short* __restrict__ Wp) {
    int idx = blockIdx.x * 256 + threadIdx.x;   // 6*4096 = 24576
    if (idx >= 24576) return;
    int mat = idx >> 12, ft = (idx >> 9) & 7, lane = (idx >> 3) & 63, j = idx & 7;
    int m = (ft >> 1) * 16 + (lane & 15);
    int k = (ft & 1) * 32 + (lane >> 4) * 8 + j;
    float w;
    if (mat == 0)      w = Win[k * 64 + m];               // W_in^T
    else if (mat <= 3) w = ipw[((mat - 1) * 64 + m) * 64 + k];
    else if (mat == 4) w = outw[m * 64 + k];
    else               w = wout[m * 64 + k];
    short hi = f2bf(w);
    float hif = __uint_as_float(((unsigned)(unsigned short)hi) << 16);
    short lo = f2bf(w - hif);
    int base = mat * 8192 + ft * 1024 + lane * 8 + j;
    Wp[base] = hi;
    Wp[base + 512] = lo;
}

// ---------------------------------------------------------------------------
// Kernel 0b: adjacency -> per-lane 16-bit mask words, pre-permuted to the
// 32x32 S^T fragment layout. Bit r of Mg[(qt2*11+kt2)*64+lane] = valid for
//   q = qt2*32 + (lane&31), key = kt2*32 + (r&3) + 8*(r>>2) + 4*(lane>>5).
// 31 KB total, L2/L1-resident; one dword load per lane per tile in kattn.
// ---------------------------------------------------------------------------
__global__ __launch_bounds__(256) void kbias(const int* __restrict__ adj,
                                             unsigned* __restrict__ Mg) {
    int idx = blockIdx.x * 256 + threadIdx.x;   // 11*11*64 = 7744
    if (idx >= QT2 * QT2 * 64) return;
    int lane = idx & 63, kt2 = (idx >> 6) % QT2, qt2 = idx / (QT2 * 64);
    int l31 = lane & 31, hi = lane >> 5;
    int q = qt2 * 32 + l31;
    unsigned m = 0;
#pragma unroll
    for (int r = 0; r < 16; ++r) {
        int key = kt2 * 32 + (r & 3) + 8 * (r >> 2) + 4 * hi;
        bool valid = (q < NN) && (key < NN) &&
                     (q == key || adj[q * NN + key] != 0);
        m |= (valid ? 1u : 0u) << r;
    }
    Mg[idx] = m;
}

// ---------------------------------------------------------------------------
// Kernel 1: fused x -> h -> Q,K,V via bf16x3 MFMA (unchanged from r6/r8).
// LDS weight staging; dense global_load_lds x-stage; head-major stores.
// LDS 80KB -> 2 blocks/CU.
// ---------------------------------------------------------------------------
__global__ __launch_bounds__(256, 2) void kqkv(const float* __restrict__ X,
                                               const float* __restrict__ bin,
                                               const float* __restrict__ ipb,
                                               const short* __restrict__ Wp,
                                               short* __restrict__ Q,
                                               short* __restrict__ Kb,
                                               short* __restrict__ Vb) {
    __shared__ short wl[32768];     // mats 0..3 frag-linear (65,536 B)
    __shared__ __align__(16) short hf[4][2048];   // per-wave x-stage/h-frag overlay
    int tid = threadIdx.x;
    {   // stage weights (one-time)
        const uint4* src = (const uint4*)Wp;
        uint4* dst = (uint4*)wl;
#pragma unroll
        for (int i = 0; i < 16; ++i) dst[tid + i * 256] = src[tid + i * 256];
    }
    __syncthreads();

    int wave = tid >> 6, lane = tid & 63, quad = lane >> 4, l15 = lane & 15;
    short* hfw = hf[wave];
    char* hfb = (char*)hfw;

    int srow = lane >> 4;       // staging: row within 4-row group
    int sslot = lane & 15;      // staging: LDS 16B slot within row
    int stride = gridDim.x * 4;

    int tile = blockIdx.x * 4 + wave;
    {   // prologue: stage x(tile): instr i covers rows 4i..4i+3 densely
        const char* xt = (const char*)X + (size_t)tile * 4096;
#pragma unroll
        for (int i = 0; i < 4; ++i) {
            int r = i * 4 + srow;
            gload16(xt + r * 256 + ((sslot ^ r) << 4), hfb + i * 1024 + lane * 16);
        }
    }

    while (tile < NTILES) {
        asm volatile("s_waitcnt vmcnt(0)" ::: "memory");
        __builtin_amdgcn_sched_barrier(0);

        // ---- x B-frags from swizzled LDS (fp32 -> hi/lo bf16) ----
        BF8 xbh[2], xbl[2];
#pragma unroll
        for (int kc = 0; kc < 2; ++kc) {
            float e[8];
#pragma unroll
            for (int h = 0; h < 2; ++h) {
                int slot = (kc * 8 + quad * 2 + h) ^ l15;
                float4 v = *(const float4*)(hfb + l15 * 256 + slot * 16);
                e[h * 4 + 0] = v.x; e[h * 4 + 1] = v.y;
                e[h * 4 + 2] = v.z; e[h * 4 + 3] = v.w;
            }
            unsigned hh[4], ll[4];
#pragma unroll
            for (int p = 0; p < 4; ++p) {
                hh[p] = pk2(e[2 * p], e[2 * p + 1]);
                float f0 = __uint_as_float(hh[p] << 16);
                float f1 = __uint_as_float(hh[p] & 0xFFFF0000u);
                ll[p] = pk2(e[2 * p] - f0, e[2 * p + 1] - f1);
            }
#pragma unroll
            for (int p = 0; p < 4; ++p) { xbh[kc].u[p] = hh[p]; xbl[kc].u[p] = ll[p]; }
        }

        // ---- GEMM1: h^T = W_in^T x^T + b_in ----
#pragma unroll
        for (int mt = 0; mt < 4; ++mt) {
            float4 bv = *(const float4*)(bin + mt * 16 + quad * 4);
            f32x4 acc = {bv.x, bv.y, bv.z, bv.w};
#pragma unroll
            for (int kc = 0; kc < 2; ++kc) {
                const short* ap = wl + (mt * 2 + kc) * 1024 + lane * 8;
                bf16x8 ah = *(const bf16x8*)ap;
                bf16x8 al = *(const bf16x8*)(ap + 512);
                acc = __builtin_amdgcn_mfma_f32_16x16x32_bf16(ah, xbh[kc].v, acc, 0, 0, 0);
                acc = __builtin_amdgcn_mfma_f32_16x16x32_bf16(ah, xbl[kc].v, acc, 0, 0, 0);
                acc = __builtin_amdgcn_mfma_f32_16x16x32_bf16(al, xbh[kc].v, acc, 0, 0, 0);
            }
            // write h hi/lo frags: F = mt*16+quad*4+r, R = l15
            int kc2 = mt >> 1;
            int lane2 = ((mt & 1) * 2 + (quad >> 1)) * 16 + l15;
            int jb = (quad & 1) * 4;
            unsigned u01 = pk2(acc[0], acc[1]), u23 = pk2(acc[2], acc[3]);
            uint2 wh; wh.x = u01; wh.y = u23;
            *(uint2*)(hfw + kc2 * 1024 + lane2 * 8 + jb) = wh;
            float f0 = __uint_as_float(u01 << 16), f1 = __uint_as_float(u01 & 0xFFFF0000u);
            float f2 = __uint_as_float(u23 << 16), f3 = __uint_as_float(u23 & 0xFFFF0000u);
            uint2 wlo; wlo.x = pk2(acc[0] - f0, acc[1] - f1);
            wlo.y = pk2(acc[2] - f2, acc[3] - f3);
            *(uint2*)(hfw + kc2 * 1024 + 512 + lane2 * 8 + jb) = wlo;
        }

        // ---- h B-frags (wave-private readback) ----
        BF8 hbh[2], hbl[2];
#pragma unroll
        for (int kc = 0; kc < 2; ++kc) {
            hbh[kc].v = *(const bf16x8*)(hfw + kc * 1024 + lane * 8);
            hbl[kc].v = *(const bf16x8*)(hfw + kc * 1024 + 512 + lane * 8);
        }

        // drain LDS reads, then overlay-stage next tile (h region dead)
        asm volatile("s_waitcnt lgkmcnt(0)" ::: "memory");
        __builtin_amdgcn_sched_barrier(0);

        int nt = tile + stride;
        if (nt < NTILES) {
            const char* xt = (const char*)X + (size_t)nt * 4096;
#pragma unroll
            for (int i = 0; i < 4; ++i) {
                int r = i * 4 + srow;
                gload16(xt + r * 256 + ((sslot ^ r) << 4), hfb + i * 1024 + lane * 16);
            }
        }

        // ---- GEMM2-4: q^T,k^T,v^T = W_t h^T + b_t ----
        size_t row = (size_t)tile * 16 + l15;
#pragma unroll
        for (int t = 0; t < 3; ++t) {
            short* Out = (t == 0) ? Q : (t == 1) ? Kb : Vb;
            float sc = (t == 0) ? QSC : 1.0f;
#pragma unroll
            for (int mt = 0; mt < 4; ++mt) {
                float4 bv = *(const float4*)(ipb + t * 64 + mt * 16 + quad * 4);
                f32x4 acc = {bv.x, bv.y, bv.z, bv.w};
#pragma unroll
                for (int kc = 0; kc < 2; ++kc) {
                    const short* ap = wl + (1 + t) * 8192 + (mt * 2 + kc) * 1024 + lane * 8;
                    bf16x8 ah = *(const bf16x8*)ap;
                    bf16x8 al = *(const bf16x8*)(ap + 512);
                    acc = __builtin_amdgcn_mfma_f32_16x16x32_bf16(ah, hbh[kc].v, acc, 0, 0, 0);
                    acc = __builtin_amdgcn_mfma_f32_16x16x32_bf16(ah, hbl[kc].v, acc, 0, 0, 0);
                    acc = __builtin_amdgcn_mfma_f32_16x16x32_bf16(al, hbh[kc].v, acc, 0, 0, 0);
                }
                uint2 st; st.x = pk2(acc[0] * sc, acc[1] * sc);
                st.y = pk2(acc[2] * sc, acc[3] * sc);
                // head-major store: head == mt; 64 lanes -> 512B contiguous
                *(uint2*)(Out + ((size_t)mt * NROWS + row) * 16 + quad * 4) = st;
            }
        }
        tile = nt;
    }
}

// ---------------------------------------------------------------------------
// Kernel 2: masked MHA, swapped-QK^T 32x32x16 structure.
//  Round-10: r8 single-chain body, NO VGPR cap. Evidence: r6 (256thr,
//  unbounded) = 72 VGPR, WRITE exactly = O size (no spill), 25% occ, 88us.
//  r8 ((512,6) cap~85) = 40 VGPR + ~68MB excess WRITE (partial spill),
//  47% occ, 79.5us. r9 ((512,4) dual-chain) = catastrophic spill (583MB
//  WRITE, 253us). Unbounded 512-thr should land ~72-110 VGPR -> 5-7
//  waves/SIMD via HW limit (2-3 blocks/CU), keeping r8's occupancy WITHOUT
//  the spill tax. Falsifiable: WRITE must drop 111 -> ~43MB.
//  V in LDS (shared by 8 waves); K/mask from global/L2 w/ 1-tile prefetch.
// ---------------------------------------------------------------------------
__global__ __launch_bounds__(512) void kattn(const short* __restrict__ Q,
                                             const short* __restrict__ K,
                                             const short* __restrict__ V,
                                             const unsigned* __restrict__ Mg,
                                             float* __restrict__ O) {
    __shared__ __align__(16) short vsT[17 * 360];     // [d][kn] + ones row 16

    // XCD-aware decode: xcd = b&7, slot = b>>3; i = (slot>>2)*8 + xcd,
    // head = slot&3. Bijective over 2048 = 512 i x 4 heads.
    int b = blockIdx.x;
    int xcd = b & 7, slot = b >> 3;
    int i = (slot >> 2) * 8 + xcd, head = slot & 3;
    const short* Kg  = K + ((size_t)head * NROWS + (size_t)i * NN) * 16;
    const short* Vbp = V + ((size_t)head * NROWS + (size_t)i * NN) * 16;
    const short* Qb  = Q + ((size_t)head * NROWS + (size_t)i * NN) * 16;
    float*       Ob  = O + ((size_t)head * NROWS + (size_t)i * NN) * 16;
    int tid = threadIdx.x;

    for (int kn = tid; kn < 352; kn += 512) {
        bf16x8 va = {0,0,0,0,0,0,0,0}, vb = {0,0,0,0,0,0,0,0};
        if (kn < NN) {
            va = *(const bf16x8*)(Vbp + (size_t)kn * 16);
            vb = *(const bf16x8*)(Vbp + (size_t)kn * 16 + 8);
        }
#pragma unroll
        for (int d = 0; d < 8; ++d) vsT[d * 360 + kn] = va[d];
#pragma unroll
        for (int d = 0; d < 8; ++d) vsT[(8 + d) * 360 + kn] = vb[d];
    }
    for (int kn = tid; kn < 360; kn += 512) vsT[16 * 360 + kn] = (short)0x3F80; // 1.0
    __syncthreads();   // the only barrier

    int wave = tid >> 6, lane = tid & 63;
    int l31 = lane & 31, hi = lane >> 5, l15 = lane & 15;
    // B-frag V row: d = lane&31 for d<16, else the ones row (broadcast)
    const short* vrow = vsT + (l31 < 16 ? l31 : 16) * 360 + hi * 8;
    const short* kgl = Kg + (size_t)l31 * 16 + hi * 8;   // per-lane K base

    f32x16 cz = {};   // loop-invariant zero C-operand

    for (int qt2 = wave; qt2 < QT2; qt2 += 8) {
        int qr = qt2 * 32 + l31; if (qr > NN - 1) qr = NN - 1;     // dup pad rows
        bf16x8 bq = *(const bf16x8*)(Qb + (size_t)qr * 16 + hi * 8);
        f32x16 acc = {};
        const unsigned* mgp = Mg + (size_t)(qt2 * QT2) * 64 + lane;

        // prefetch tile 0 operands (K from global/L2)
        bf16x8 ak = *(const bf16x8*)(kgl);
        unsigned mw = mgp[0];

        for (int kt2 = 0; kt2 < QT2; ++kt2) {
            f32x16 s = __builtin_amdgcn_mfma_f32_32x32x16_bf16(ak, bq, cz, 0, 0, 0);

            // prefetch next tile's A-frag + mask word while exp/pack runs
            int nk = kt2 + 1; nk = (nk == QT2) ? 0 : nk;
            ak = *(const bf16x8*)(kgl + (size_t)nk * 512);
            unsigned mwn = mgp[nk * 64];
            bf16x8 v0 = *(const bf16x8*)(vrow + kt2 * 32);
            bf16x8 v1 = *(const bf16x8*)(vrow + kt2 * 32 + 16);

            float p[16];
#pragma unroll
            for (int r = 0; r < 16; ++r)
                p[r] = maskp(__builtin_amdgcn_exp2f(s[r]), mw, r);

            // p[r] = P[q=l31][key_local = (r&3)+8*(r>>2)+4*hi]; pack pairs and
            // permlane-swap into PV A-frag order (keys hi*8+j per lane).
            unsigned w0 = pk2(p[0],  p[1]),  w1 = pk2(p[2],  p[3]);
            unsigned w2 = pk2(p[4],  p[5]),  w3 = pk2(p[6],  p[7]);
            unsigned w4 = pk2(p[8],  p[9]),  w5 = pk2(p[10], p[11]);
            unsigned w6 = pk2(p[12], p[13]), w7 = pk2(p[14], p[15]);
            u32x2 s02 = __builtin_amdgcn_permlane32_swap(w0, w2, false, false);
            u32x2 s13 = __builtin_amdgcn_permlane32_swap(w1, w3, false, false);
            u32x2 s46 = __builtin_amdgcn_permlane32_swap(w4, w6, false, false);
            u32x2 s57 = __builtin_amdgcn_permlane32_swap(w5, w7, false, false);
            BF8 pa0, pa1;
            pa0.u[0] = s02[0]; pa0.u[1] = s13[0]; pa0.u[2] = s02[1]; pa0.u[3] = s13[1];
            pa1.u[0] = s46[0]; pa1.u[1] = s57[0]; pa1.u[2] = s46[1]; pa1.u[3] = s57[1];

            acc = __builtin_amdgcn_mfma_f32_32x32x16_bf16(pa0.v, v0, acc, 0, 0, 0);
            acc = __builtin_amdgcn_mfma_f32_32x32x16_bf16(pa1.v, v1, acc, 0, 0, 0);
            mw = mwn;
        }

        // acc[r]: D[q = qt2*32 + (r&3)+8*(r>>2)+4*hi][col = lane&31]
        //   cols 0..15 numerator (d), cols 16..31 denominator.
#pragma unroll
        for (int r = 0; r < 16; ++r) {
            float den = __shfl_xor(acc[r], 16, 64);
            float inv = __builtin_amdgcn_rcpf(den);
            inv = inv * (2.0f - den * inv);          // 1 Newton step: ~1ulp
            int qn = qt2 * 32 + (r & 3) + 8 * (r >> 2) + 4 * hi;
            if (l31 < 16 && qn < NN)
                Ob[(size_t)qn * 16 + l15] = acc[r] * inv;
        }
    }
}

// ---------------------------------------------------------------------------
// Kernel 3: o -> out_proj -> W_out -> exact GELU -> transposed store
// (unchanged from r6/r8). LDS 48KB -> 3 blocks/CU.
// ---------------------------------------------------------------------------
__global__ __launch_bounds__(256, 2) void kfinal(const float* __restrict__ Ob,
                                                 const float* __restrict__ outb,
                                                 const float* __restrict__ boutv,
                                                 const short* __restrict__ Wp,
                                                 float* __restrict__ Yout) {
    __shared__ short wl[16384];     // mats 4,5 (32,768 B)
    __shared__ __align__(16) short hf[4][2048];   // t1 frags, then y-transpose
    int tid = threadIdx.x;
    {
        const uint4* src = (const uint4*)Wp;
        uint4* dst = (uint4*)wl;
#pragma unroll
        for (int i = 0; i < 8; ++i) dst[tid + i * 256] = src[4096 + tid + i * 256];
    }
    __syncthreads();

    int wave = tid >> 6, lane = tid & 63, quad = lane >> 4, l15 = lane & 15;
    short* hfw = hf[wave];

    for (int tile = blockIdx.x * 4 + wave; tile < NTILES; tile += gridDim.x * 4) {
        size_t row = (size_t)tile * 16 + l15;

        BF8 obh[2], obl[2];
#pragma unroll
        for (int kc = 0; kc < 2; ++kc) {
            // head-major O: h = kc*32+quad*8 -> head = kc*2+(quad>>1),
            // idx = (quad&1)*8
            const float* xp = Ob + ((size_t)(kc * 2 + (quad >> 1)) * NROWS + row) * 16
                              + (quad & 1) * 8;
            float4 v0 = *(const float4*)xp;
            float4 v1 = *(const float4*)(xp + 4);
            float e[8] = {v0.x, v0.y, v0.z, v0.w, v1.x, v1.y, v1.z, v1.w};
            unsigned hh[4], ll[4];
#pragma unroll
            for (int p = 0; p < 4; ++p) {
                hh[p] = pk2(e[2 * p], e[2 * p + 1]);
                float f0 = __uint_as_float(hh[p] << 16);
                float f1 = __uint_as_float(hh[p] & 0xFFFF0000u);
                ll[p] = pk2(e[2 * p] - f0, e[2 * p + 1] - f1);
            }
#pragma unroll
            for (int p = 0; p < 4; ++p) { obh[kc].u[p] = hh[p]; obl[kc].u[p] = ll[p]; }
        }

        // GEMM5: t1^T = out_w o^T + out_b
#pragma unroll
        for (int mt = 0; mt < 4; ++mt) {
            float4 bv = *(const float4*)(outb + mt * 16 + quad * 4);
            f32x4 acc = {bv.x, bv.y, bv.z, bv.w};
#pragma unroll
            for (int kc = 0; kc < 2; ++kc) {
                const short* ap = wl + (mt * 2 + kc) * 1024 + lane * 8;
                bf16x8 ah = *(const bf16x8*)ap;
                bf16x8 al = *(const bf16x8*)(ap + 512);
                acc = __builtin_amdgcn_mfma_f32_16x16x32_bf16(ah, obh[kc].v, acc, 0, 0, 0);
                acc = __builtin_amdgcn_mfma_f32_16x16x32_bf16(ah, obl[kc].v, acc, 0, 0, 0);
                acc = __builtin_amdgcn_mfma_f32_16x16x32_bf16(al, obh[kc].v, acc, 0, 0, 0);
            }
            int kc2 = mt >> 1;
            int lane2 = ((mt & 1) * 2 + (quad >> 1)) * 16 + l15;
            int jb = (quad & 1) * 4;
            unsigned u01 = pk2(acc[0], acc[1]), u23 = pk2(acc[2], acc[3]);
            uint2 wh; wh.x = u01; wh.y = u23;
            *(uint2*)(hfw + kc2 * 1024 + lane2 * 8 + jb) = wh;
            float f0 = __uint_as_float(u01 << 16), f1 = __uint_as_float(u01 & 0xFFFF0000u);
            float f2 = __uint_as_float(u23 << 16), f3 = __uint_as_float(u23 & 0xFFFF0000u);
            uint2 wlo; wlo.x = pk2(acc[0] - f0, acc[1] - f1);
            wlo.y = pk2(acc[2] - f2, acc[3] - f3);
            *(uint2*)(hfw + kc2 * 1024 + 512 + lane2 * 8 + jb) = wlo;
        }

        BF8 tbh[2], tbl[2];
#pragma unroll
        for (int kc = 0; kc < 2; ++kc) {
            tbh[kc].v = *(const bf16x8*)(hfw + kc * 1024 + lane * 8);
            tbl[kc].v = *(const bf16x8*)(hfw + kc * 1024 + 512 + lane * 8);
        }

        // GEMM6: y^T = W_out t1^T + b_out; GELU; LDS transpose; 256B stores
        float* yf = (float*)hfw;     // t1 frags dead after tbh/tbl readback
#pragma unroll
        for (int mt = 0; mt < 4; ++mt) {
            float4 bv = *(const float4*)(boutv + mt * 16 + quad * 4);
            f32x4 acc = {bv.x, bv.y, bv.z, bv.w};
#pragma unroll
            for (int kc = 0; kc < 2; ++kc) {
                const short* ap = wl + 8192 + (mt * 2 + kc) * 1024 + lane * 8;
                bf16x8 ah = *(const bf16x8*)ap;
                bf16x8 al = *(const bf16x8*)(ap + 512);
                acc = __builtin_amdgcn_mfma_f32_16x16x32_bf16(ah, tbh[kc].v, acc, 0, 0, 0);
                acc = __builtin_amdgcn_mfma_f32_16x16x32_bf16(ah, tbl[kc].v, acc, 0, 0, 0);
                acc = __builtin_amdgcn_mfma_f32_16x16x32_bf16(al, tbh[kc].v, acc, 0, 0, 0);
            }
            float4 yv;
            yv.x = 0.5f * acc[0] * (1.0f + erff(acc[0] * 0.70710678118654752f));
            yv.y = 0.5f * acc[1] * (1.0f + erff(acc[1] * 0.70710678118654752f));
            yv.z = 0.5f * acc[2] * (1.0f + erff(acc[2] * 0.70710678118654752f));
            yv.w = 0.5f * acc[3] * (1.0f + erff(acc[3] * 0.70710678118654752f));
            int cblk = mt * 4 + quad;                 // 4-float column block
            int pos = cblk ^ (l15 & 7);               // bank-spread swizzle
            *(float4*)(yf + l15 * 64 + pos * 4) = yv;
        }
#pragma unroll
        for (int s = 0; s < 4; ++s) {
            int rr = s * 4 + (lane >> 4);             // row within tile
            float4 w = *(const float4*)(yf + rr * 64 + ((l15 ^ (rr & 7)) * 4));
            unsigned rw2 = (unsigned)(tile * 16 + rr);
            unsigned ii2 = rw2 / NN, n2 = rw2 - ii2 * NN;
            size_t ob2 = (((size_t)(ii2 >> 6) * NN + n2) * 64 + (ii2 & 63)) * 64;
            *(float4*)(Yout + ob2 + l15 * 4) = w;     // 16 lanes = 256B row
        }
    }
}

// ---------------------------------------------------------------------------
extern "C" void kernel_launch(void* const* d_in, const int* in_sizes, int n_in,
                              void* d_out, int out_size, void* d_ws, size_t ws_size,
                              hipStream_t stream) {
    const float* x    = (const float*)d_in[0];
    const int*   adj  = (const int*)  d_in[1];
    const float* W_in = (const float*)d_in[2];
    const float* b_in = (const float*)d_in[3];
    const float* ipw  = (const float*)d_in[4];
    const float* ipb  = (const float*)d_in[5];
    const float* outw = (const float*)d_in[6];
    const float* outb = (const float*)d_in[7];
    const float* wout = (const float*)d_in[8];
    const float* bout = (const float*)d_in[9];
    float* out = (float*)d_out;

    char* wsb = (char*)d_ws;
    short* bufQ = (short*)(wsb);                        // 2*RELEM B (head-major)
    short* bufK = (short*)(wsb + 2 * RELEM);
    short* bufV = (short*)(wsb + 4 * RELEM);
    float* bufO = (float*)(wsb + 6 * RELEM);            // 4*RELEM B (head-major)
    short* Wp   = (short*)(wsb + 10 * RELEM);           // 98,304 B
    unsigned* Mg = (unsigned*)(wsb + 10 * RELEM + 98304); // 11*11*64*4 = 30,976 B

    hipLaunchKernelGGL(kprep,  dim3(96),  dim3(256), 0, stream, W_in, ipw, outw, wout, Wp);
    hipLaunchKernelGGL(kbias,  dim3(31),  dim3(256), 0, stream, adj, Mg);
    hipLaunchKernelGGL(kqkv,   dim3(512), dim3(256), 0, stream,
                       x, b_in, ipb, Wp, bufQ, bufK, bufV);
    hipLaunchKernelGGL(kattn,  dim3(512 * 4), dim3(512), 0, stream,
                       bufQ, bufK, bufV, Mg, bufO);
    hipLaunchKernelGGL(kfinal, dim3(768), dim3(256), 0, stream,
                       bufO, outb, bout, Wp, out);
}